// Round 1
// baseline (2110.289 us; speedup 1.0000x reference)
//
#include <hip/hip_runtime.h>
#include <cstdint>
#include <cstddef>

#define D       512
#define NROWS   16384
#define NCODES  8192
#define BM      64
#define BC      128
#define BK      16
#define NTHREADS 512

// ---------------------------------------------------------------------------
// Kernel 1: e2[c] = sum_d embed[c][d]^2.  One wave per code row.
// ---------------------------------------------------------------------------
__global__ void vq_e2_kernel(const float* __restrict__ embed,
                             float* __restrict__ e2) {
  const int w    = (blockIdx.x * blockDim.x + threadIdx.x) >> 6;  // wave id = code row
  const int lane = threadIdx.x & 63;
  const float* p = embed + (size_t)w * D + lane * 8;
  const float4 a = *(const float4*)p;
  const float4 b = *(const float4*)(p + 4);
  float s = a.x * a.x + a.y * a.y + a.z * a.z + a.w * a.w +
            b.x * b.x + b.y * b.y + b.z * b.z + b.w * b.w;
#pragma unroll
  for (int m = 32; m >= 1; m >>= 1) s += __shfl_xor(s, m, 64);
  if (lane == 0) e2[w] = s;
}

// ---------------------------------------------------------------------------
// Kernel 2: fused distance-GEMM + argmin + gather + commit loss.
//   Block: 512 threads (8 waves), BM=64 x-rows.
//   x tile resident in LDS k-major (xs[k][row], 128 KiB).
//   embed streamed in BC=128-code tiles, k-transposed, double-buffered BK=16.
//   Thread (tr = tid>>5, tc = tid&31) owns rows tr*4..+3, codes tc*4..+3.
//   score = e2[c] - 2*dot(x,e)   (x^2 row-constant -> same argmin as cdist^2)
// ---------------------------------------------------------------------------
__global__ __launch_bounds__(NTHREADS) void vq_main_kernel(
    const float* __restrict__ x, const float* __restrict__ embed,
    const float* __restrict__ e2g, float* __restrict__ out_q,
    float* __restrict__ out_idx, float* __restrict__ out_loss) {
  __shared__ float xs[D][BM];            // 131072 B, k-major
  __shared__ float es[2][BK][BC + 4];    // 16896 B, k-major, padded stride 132
  __shared__ int   rowbest[BM];

  const int tid  = threadIdx.x;
  const int tc4  = (tid & 31) * 4;   // first code of this thread within tile
  const int tr   = tid >> 5;         // row group 0..15
  const int tr4  = tr * 4;
  const int row0 = blockIdx.x * BM;

  // ---- stage x tile, transposed to k-major ----
  {
    const int r  = tid & 63;          // 64 distinct rows per wave -> conflict-free writes
    const int kb = (tid >> 6) * 64;   // 8 groups cover k=0..511
    const float* xp = x + (size_t)(row0 + r) * D + kb;
#pragma unroll
    for (int kk = 0; kk < 64; kk += 4) {
      const float4 v = *(const float4*)(xp + kk);
      xs[kb + kk + 0][r] = v.x;
      xs[kb + kk + 1][r] = v.y;
      xs[kb + kk + 2][r] = v.z;
      xs[kb + kk + 3][r] = v.w;
    }
  }

  float bestv[4];
  int   besti[4];
#pragma unroll
  for (int i = 0; i < 4; ++i) { bestv[i] = 3.4e38f; besti[i] = 0; }

  // staging map for es: thread -> (code sc, k offset sk), one float4 per chunk
  const int sc = tid >> 2;        // 0..127
  const int sk = (tid & 3) * 4;   // 0,4,8,12

  __syncthreads();

  for (int ct = 0; ct < NCODES / BC; ++ct) {
    const int c0 = ct * BC;

    // stage chunk 0 into buffer 0
    {
      const float4 v = *(const float4*)(embed + (size_t)(c0 + sc) * D + sk);
      es[0][sk + 0][sc] = v.x;
      es[0][sk + 1][sc] = v.y;
      es[0][sk + 2][sc] = v.z;
      es[0][sk + 3][sc] = v.w;
    }

    float acc[4][4];
#pragma unroll
    for (int i = 0; i < 4; ++i)
#pragma unroll
      for (int j = 0; j < 4; ++j) acc[i][j] = 0.f;

    __syncthreads();

    int buf = 0;
    for (int kc = 0; kc < D / BK; ++kc) {
      // prefetch next k-chunk into the other buffer
      if (kc + 1 < D / BK) {
        const float4 v = *(const float4*)(embed + (size_t)(c0 + sc) * D +
                                          (kc + 1) * BK + sk);
        es[buf ^ 1][sk + 0][sc] = v.x;
        es[buf ^ 1][sk + 1][sc] = v.y;
        es[buf ^ 1][sk + 2][sc] = v.z;
        es[buf ^ 1][sk + 3][sc] = v.w;
      }
      const int kb = kc * BK;
#pragma unroll
      for (int k = 0; k < BK; ++k) {
        const float4 xv = *(const float4*)&xs[kb + k][tr4];
        const float4 ev = *(const float4*)&es[buf][k][tc4];
        const float ax[4] = {xv.x, xv.y, xv.z, xv.w};
        const float bx[4] = {ev.x, ev.y, ev.z, ev.w};
#pragma unroll
        for (int i = 0; i < 4; ++i)
#pragma unroll
          for (int j = 0; j < 4; ++j)
            acc[i][j] = fmaf(ax[i], bx[j], acc[i][j]);
      }
      __syncthreads();
      buf ^= 1;
    }

    // epilogue for this code tile: score = e2 - 2*dot, update running argmin
    const float4 e2v = *(const float4*)(e2g + c0 + tc4);
    const float e2a[4] = {e2v.x, e2v.y, e2v.z, e2v.w};
#pragma unroll
    for (int j = 0; j < 4; ++j) {
      const int c = c0 + tc4 + j;
#pragma unroll
      for (int i = 0; i < 4; ++i) {
        const float scv = fmaf(-2.f, acc[i][j], e2a[j]);
        if (scv < bestv[i]) { bestv[i] = scv; besti[i] = c; }  // strict < keeps lowest idx
      }
    }
  }

  // ---- cross-thread argmin: 32 tc-threads per row live in one half-wave ----
#pragma unroll
  for (int i = 0; i < 4; ++i) {
    float v  = bestv[i];
    int   bi = besti[i];
#pragma unroll
    for (int m = 16; m >= 1; m >>= 1) {
      const float ov = __shfl_xor(v, m, 64);
      const int   oi = __shfl_xor(bi, m, 64);
      if (ov < v || (ov == v && oi < bi)) { v = ov; bi = oi; }
    }
    if ((tid & 31) == 0) {
      rowbest[tr4 + i] = bi;
      out_idx[row0 + tr4 + i] = (float)bi;
    }
  }
  __syncthreads();

  // ---- gather winning embed rows + commitment loss ----
  float lsum = 0.f;
  {
    const int r  = tid >> 3;         // 8 threads per row
    const int kb = (tid & 7) * 64;   // 64 floats each
    const int bi = rowbest[r];
    const float* ep = embed + (size_t)bi * D + kb;
    const float* xp = x + (size_t)(row0 + r) * D + kb;
    float* qp = out_q + (size_t)(row0 + r) * D + kb;
#pragma unroll
    for (int kk = 0; kk < 64; kk += 4) {
      const float4 e4 = *(const float4*)(ep + kk);
      const float4 x4 = *(const float4*)(xp + kk);
      *(float4*)(qp + kk) = e4;  // quantize_st == quantize numerically
      const float d0 = e4.x - x4.x, d1 = e4.y - x4.y;
      const float d2 = e4.z - x4.z, d3 = e4.w - x4.w;
      lsum += d0 * d0 + d1 * d1 + d2 * d2 + d3 * d3;
    }
  }
#pragma unroll
  for (int m = 32; m >= 1; m >>= 1) lsum += __shfl_xor(lsum, m, 64);
  if ((tid & 63) == 0)
    atomicAdd(out_loss, lsum * (1.f / (float)((size_t)NROWS * D)));
}

// ---------------------------------------------------------------------------
extern "C" void kernel_launch(void* const* d_in, const int* in_sizes, int n_in,
                              void* d_out, int out_size, void* d_ws,
                              size_t ws_size, hipStream_t stream) {
  (void)in_sizes; (void)n_in; (void)out_size; (void)ws_size;
  const float* x     = (const float*)d_in[0];
  const float* embed = (const float*)d_in[1];
  float* e2       = (float*)d_ws;                       // 8192 floats scratch
  float* out_q    = (float*)d_out;                      // [16384][512]
  float* out_idx  = out_q + (size_t)NROWS * D;          // [16384] as float
  float* out_loss = out_idx + NROWS;                    // [1]

  vq_e2_kernel<<<NCODES / 4, 256, 0, stream>>>(embed, e2);
  hipMemsetAsync(out_loss, 0, sizeof(float), stream);
  vq_main_kernel<<<NROWS / BM, NTHREADS, 0, stream>>>(x, embed, e2, out_q,
                                                      out_idx, out_loss);
}